// Round 6
// baseline (480.878 us; speedup 1.0000x reference)
//
#include <hip/hip_runtime.h>
#include <math.h>

// ---------------------------------------------------------------------------
// DeformableFeatureAggregation — MI355X
// Pipeline (6 launches):
//   k_transpose_all : feat L0..L3 (6,256,H,W) fp32 -> featT (6,H,W,256) bf16
//   k_prep_pack     : iw->Ab bf16 ; [W_wts|W_learn]->Bb bf16 N-major ; W_out->Wob
//   k_wts_mfma      : MFMA -> logitsB bf16 (4096x2496) + learn fp32 (4096x18)
//   k_prep_tables   : per anchor: softmax -> swT bf16[8][328]; projection;
//                     per-task corner byte-offsets int4 + bilinear w float4 -> tbl
//   k_gather        : per anchor: stage swT in LDS; loop tasks with uniform
//                     16B table loads + saddr corner loads -> featsB bf16
//   k_out_mfma      : MFMA out = featsB @ W_out^T + b_out + iw (fp32)
// Workspace (float offsets):
//   featT  : ush 0..22978560          (f 0..11489280)
//   logitsB: f 11489280  (4096x2496 ush)      -> 16601088
//   featsB : f 16601088  (4096x256 ush)       -> 17125376
//   learn  : f 17125376  (4096x18 f)          -> 17199104
//   Ab     : f 17199104  (4096x256 ush)       -> 17723392
//   Bb     : f 17723392  (2560x256 ush)       -> 18051072
//   Wob    : f 18051072  (256x256 ush)        -> 18083840
//   swT    : f 18083840  (4096x2624 ush)      -> 23457792
//   tbl    : f 23457792  (4096x312x8 f)       -> 33681408  (~135 MB)
// ---------------------------------------------------------------------------

#define FEATT_L0 0
#define FEATT_L1 17301504
#define FEATT_L2 21626880
#define FEATT_L3 22708224
#define WS_LOGB 11489280
#define WS_FEATB 16601088
#define WS_LEARN 17125376
#define WS_AB 17199104
#define WS_BB 17723392
#define WS_WOB 18051072
#define WS_SWT 18083840
#define WS_TBL 23457792

typedef float v2f __attribute__((ext_vector_type(2)));
typedef __attribute__((ext_vector_type(8))) short bf16x8;
typedef __attribute__((ext_vector_type(4))) float f32x4;

__device__ const float FIXS[7][3] = {
    {0.f, 0.f, 0.f},  {0.45f, 0.f, 0.f}, {-0.45f, 0.f, 0.f}, {0.f, 0.45f, 0.f},
    {0.f, -0.45f, 0.f}, {0.f, 0.f, 0.45f}, {0.f, 0.f, -0.45f}};

__device__ __forceinline__ unsigned int f2bf(float f) {
  unsigned int u = __float_as_uint(f);
  u += 0x7fffu + ((u >> 16) & 1u);  // RTNE
  return u >> 16;
}
__device__ __forceinline__ float bf2f(unsigned short u) {
  return __uint_as_float(((unsigned int)u) << 16);
}

// All 4 levels: (6,256,H,W) fp32 -> (6,H,W,256) bf16. grid (12, 64, 48)
__global__ __launch_bounds__(256) void k_transpose_all(
    const float* __restrict__ f0, const float* __restrict__ f1,
    const float* __restrict__ f2, const float* __restrict__ f3,
    unsigned short* __restrict__ featT) {
  const int bx = blockIdx.x;
  const float* src;
  unsigned short* dst;
  int H, W, xt;
  if (bx < 6)       { src = f0; dst = featT + FEATT_L0; H = 64; W = 176; xt = bx * 32; }
  else if (bx < 9)  { src = f1; dst = featT + FEATT_L1; H = 32; W = 88;  xt = (bx - 6) * 32; }
  else if (bx < 11) { src = f2; dst = featT + FEATT_L2; H = 16; W = 44;  xt = (bx - 9) * 32; }
  else              { src = f3; dst = featT + FEATT_L3; H = 8;  W = 22;  xt = 0; }
  const int y = blockIdx.y;
  if (y >= H) return;
  __shared__ float tile[32][33];
  const int tid = threadIdx.x;
  const int i = tid & 31;
  const int j = tid >> 5;
  const int c = blockIdx.z >> 3;
  const int cht = (blockIdx.z & 7) * 32;
#pragma unroll
  for (int jj = j; jj < 32; jj += 8) {
    int x = xt + i;
    float v = 0.f;
    if (x < W) v = src[((c * 256 + cht + jj) * H + y) * W + x];
    tile[jj][i] = v;
  }
  __syncthreads();
#pragma unroll
  for (int jj = j; jj < 32; jj += 8) {
    int x = xt + jj;
    if (x < W)
      dst[(((c * H + y) * W + x) * 256) + cht + i] = (unsigned short)f2bf(tile[i][jj]);
  }
}

// Fused packing: bx<1024 -> Ab ; <1664 -> Bb tile ; else Wob tile. grid 1728.
__global__ __launch_bounds__(256) void k_prep_pack(
    const float* __restrict__ iw, const float* __restrict__ Ww,
    const float* __restrict__ Wl, const float* __restrict__ Wo,
    unsigned short* __restrict__ Ab, unsigned short* __restrict__ Bb,
    unsigned short* __restrict__ Wob) {
  __shared__ unsigned short tile[32][33];
  const int tid = threadIdx.x;
  const int bx = blockIdx.x;
  if (bx < 1024) {
    const int i = bx * 256 + tid;
    const float4 v = ((const float4*)iw)[i];
    uint2 o;
    o.x = f2bf(v.x) | (f2bf(v.y) << 16);
    o.y = f2bf(v.z) | (f2bf(v.w) << 16);
    ((uint2*)Ab)[i] = o;
    return;
  }
  const int i = tid & 31;
  const int r = tid >> 5;
  if (bx < 1664) {
    const int idx = bx - 1024;
    const int j0 = (idx % 80) * 32;
    const int k0 = (idx / 80) * 32;
#pragma unroll
    for (int rr = r; rr < 32; rr += 8) {
      const int k = k0 + rr, j = j0 + i;
      float v = 0.f;
      if (j < 2496) v = Ww[k * 2496 + j];
      else if (j < 2514) v = Wl[k * 18 + (j - 2496)];
      tile[rr][i] = (unsigned short)f2bf(v);
    }
    __syncthreads();
#pragma unroll
    for (int rr = r; rr < 32; rr += 8)
      Bb[(j0 + rr) * 256 + k0 + i] = tile[i][rr];
  } else {
    const int idx = bx - 1664;
    const int j0 = (idx & 7) * 32;
    const int k0 = (idx >> 3) * 32;
#pragma unroll
    for (int rr = r; rr < 32; rr += 8)
      tile[rr][i] = (unsigned short)f2bf(Wo[(k0 + rr) * 256 + j0 + i]);
    __syncthreads();
#pragma unroll
    for (int rr = r; rr < 32; rr += 8)
      Wob[(j0 + rr) * 256 + k0 + i] = tile[i][rr];
  }
}

// MFMA GEMM: [logits | learn] = Ab(4096x256) @ Bb^T + bias. grid (40,64)
__global__ __launch_bounds__(256) void k_wts_mfma(
    const unsigned short* __restrict__ Ab, const unsigned short* __restrict__ Bb,
    const float* __restrict__ b_wts, const float* __restrict__ b_learn,
    unsigned short* __restrict__ logitsB, float* __restrict__ learn) {
  const int tid = threadIdx.x;
  const int w = tid >> 6, lane = tid & 63;
  const int ml = lane & 15, q = lane >> 4;
  const int n0 = blockIdx.x * 64;
  const int m0 = blockIdx.y * 64;
  f32x4 acc[4] = {{0.f, 0.f, 0.f, 0.f}, {0.f, 0.f, 0.f, 0.f},
                  {0.f, 0.f, 0.f, 0.f}, {0.f, 0.f, 0.f, 0.f}};
  const unsigned short* Ap = Ab + (m0 + w * 16 + ml) * 256 + q * 8;
  const unsigned short* Bp = Bb + (n0 + ml) * 256 + q * 8;
#pragma unroll
  for (int kk = 0; kk < 8; ++kk) {
    const bf16x8 a = *(const bf16x8*)(Ap + kk * 32);
#pragma unroll
    for (int nt = 0; nt < 4; ++nt) {
      const bf16x8 b = *(const bf16x8*)(Bp + nt * 16 * 256 + kk * 32);
      acc[nt] = __builtin_amdgcn_mfma_f32_16x16x32_bf16(a, b, acc[nt], 0, 0, 0);
    }
  }
  const int rowb = m0 + w * 16 + q * 4;
#pragma unroll
  for (int nt = 0; nt < 4; ++nt) {
    const int col = n0 + nt * 16 + ml;
    if (col < 2496) {
      const float b = b_wts[col];
#pragma unroll
      for (int r = 0; r < 4; ++r)
        logitsB[(rowb + r) * 2496 + col] = (unsigned short)f2bf(acc[nt][r] + b);
    } else if (col < 2514) {
      const float b = b_learn[col - 2496];
#pragma unroll
      for (int r = 0; r < 4; ++r) {
        float v = fminf(fmaxf(acc[nt][r] + b, -9.21f), 9.21f);
        learn[(rowb + r) * 18 + (col - 2496)] = 1.f / (1.f + expf(-v)) - 0.5f;
      }
    }
  }
}

// Per anchor: softmax -> swT (bf16, transposed [g][328]); projection; per-task
// corner byte-offsets + bilinear weights -> tbl. grid 4096 x 256.
__global__ __launch_bounds__(256) void k_prep_tables(
    const float* __restrict__ anchor, const unsigned short* __restrict__ logitsB,
    const float* __restrict__ learn_g, const float* __restrict__ proj,
    const float* __restrict__ wh, unsigned int* __restrict__ swTu,
    int* __restrict__ tbl) {
  const int n = blockIdx.x;
  const int tid = threadIdx.x;
  const int lane = tid & 63;
  const int wave = tid >> 6;
  __shared__ unsigned int s_wu[1312];  // 8*328 bf16
  __shared__ float s_p2d[78][2];
  __shared__ float s_learn[18];
  unsigned short* s_w = (unsigned short*)s_wu;

  for (int i = tid; i < 2496; i += 256) {
    const int s = i >> 3, g = i & 7;
    s_w[g * 328 + s] = logitsB[n * 2496 + i];
  }
  if (tid < 18) s_learn[tid] = learn_g[n * 18 + tid];
  __syncthreads();

  // softmax per group; wave w -> groups 2w, 2w+1
#pragma unroll
  for (int gg = 0; gg < 2; ++gg) {
    unsigned short* row = &s_w[(wave * 2 + gg) * 328];
    float l[5];
    float mx = -1e30f;
#pragma unroll
    for (int i = 0; i < 5; ++i) {
      const int s = lane + i * 64;
      l[i] = (s < 312) ? bf2f(row[s]) : -1e30f;
      mx = fmaxf(mx, l[i]);
    }
    for (int off = 32; off; off >>= 1) mx = fmaxf(mx, __shfl_xor(mx, off));
    float sum = 0.f;
#pragma unroll
    for (int i = 0; i < 5; ++i) {
      l[i] = __expf(l[i] - mx);
      sum += l[i];
    }
    for (int off = 32; off; off >>= 1) sum += __shfl_xor(sum, off);
    const float inv = 1.f / sum;
#pragma unroll
    for (int i = 0; i < 5; ++i) {
      const int s = lane + i * 64;
      if (s < 312) row[s] = (unsigned short)f2bf(l[i] * inv);
    }
  }

  // projection of 78 (pt,cam) pairs
  if (tid < 78) {
    const int p = tid / 6, c = tid % 6;
    const float* an = anchor + n * 11;
    float qw = an[6], qx = an[7], qy = an[8], qz = an[9];
    const float qinv = 1.f / sqrtf(qw * qw + qx * qx + qy * qy + qz * qz);
    qw *= qinv; qx *= qinv; qy *= qinv; qz *= qinv;
    const float R00 = 1.f - 2.f * (qy * qy + qz * qz), R01 = 2.f * (qx * qy - qw * qz), R02 = 2.f * (qx * qz + qw * qy);
    const float R10 = 2.f * (qx * qy + qw * qz), R11 = 1.f - 2.f * (qx * qx + qz * qz), R12 = 2.f * (qy * qz - qw * qx);
    const float R20 = 2.f * (qx * qz - qw * qy), R21 = 2.f * (qy * qz + qw * qx), R22 = 1.f - 2.f * (qx * qx + qy * qy);
    float s0, s1, s2;
    if (p < 7) {
      s0 = FIXS[p][0]; s1 = FIXS[p][1]; s2 = FIXS[p][2];
    } else {
      const int b = (p - 7) * 3;
      s0 = s_learn[b]; s1 = s_learn[b + 1]; s2 = s_learn[b + 2];
    }
    const float vx = s0 * an[3], vy = s1 * an[4], vz = s2 * an[5];
    const float kx = R00 * vx + R10 * vy + R20 * vz + an[0];
    const float ky = R01 * vx + R11 * vy + R21 * vz + an[1];
    const float kz = R02 * vx + R12 * vy + R22 * vz + an[2];
    const float* P = proj + c * 16;
    const float h0 = P[0] * kx + P[1] * ky + P[2] * kz + P[3];
    const float h1 = P[4] * kx + P[5] * ky + P[6] * kz + P[7];
    const float h2 = P[8] * kx + P[9] * ky + P[10] * kz + P[11];
    const float zz = fmaxf(h2, 1e-5f);
    float px = h0 / zz / wh[c * 2 + 0];
    float py = h1 / zz / wh[c * 2 + 1];
    px = fminf(fmaxf(px, 0.f), 0.9999f);
    py = fminf(fmaxf(py, 0.f), 0.9999f);
    s_p2d[tid][0] = px;
    s_p2d[tid][1] = py;
  }
  __syncthreads();

  // dump softmax weights (coalesced uint)
  for (int i = tid; i < 1312; i += 256) swTu[n * 1312 + i] = s_wu[i];

  // per-task corner BYTE offsets + bilinear weights -> tbl (32 B/task)
  {
    constexpr int LBB[4] = {0, 34603008, 43253760, 45416448};   // bytes
    constexpr int CSB[4] = {5767168, 1441792, 360448, 90112};    // H*W*512
    for (int t = tid; t < 312; t += 256) {
      const int pc = t >> 2, l = t & 3;
      const int c = pc % 6;
      const int H = 64 >> l, W = 176 >> l;
      const float fx = s_p2d[pc][0] * (float)W - 0.5f;
      const float fy = s_p2d[pc][1] * (float)H - 0.5f;
      const float x0f = floorf(fx), y0f = floorf(fy);
      const float wx = fx - x0f, wy = fy - y0f;
      const int x0 = (int)x0f, y0 = (int)y0f;
      const float mx0 = (x0 >= 0) ? 1.f : 0.f;
      const float mx1 = (x0 + 1 < W) ? 1.f : 0.f;
      const float my0 = (y0 >= 0) ? 1.f : 0.f;
      const float my1 = (y0 + 1 < H) ? 1.f : 0.f;
      const int cx0 = max(x0, 0), cx1 = min(x0 + 1, W - 1);
      const int cy0 = max(y0, 0), cy1 = min(y0 + 1, H - 1);
      const int base = LBB[l] + c * CSB[l];
      int4 o;
      o.x = base + (cy0 * W + cx0) * 512;
      o.y = base + (cy0 * W + cx1) * 512;
      o.z = base + (cy1 * W + cx0) * 512;
      o.w = base + (cy1 * W + cx1) * 512;
      float4 w4;
      w4.x = (1.f - wx) * (1.f - wy) * mx0 * my0;
      w4.y = wx * (1.f - wy) * mx1 * my0;
      w4.z = (1.f - wx) * wy * mx0 * my1;
      w4.w = wx * wy * mx1 * my1;
      ((int4*)tbl)[(n * 312 + t) * 2] = o;
      ((float4*)tbl)[(n * 312 + t) * 2 + 1] = w4;
    }
  }
}

// Gather: stage swT to LDS; loop tasks with uniform 16B table loads; corner
// loads at o + lane*8. grid 4096 x 256.
__global__ __launch_bounds__(256, 6) void k_gather(
    const unsigned int* __restrict__ swTu, const int* __restrict__ tbl,
    const unsigned short* __restrict__ featT,
    unsigned short* __restrict__ featsB) {
  const int n = blockIdx.x;
  const int tid = threadIdx.x;
  const int lane = tid & 63;
  const int wave = tid >> 6;
  __shared__ unsigned int s_wu[1312];
  __shared__ float s_red[4][256];
  for (int i = tid; i < 1312; i += 256) s_wu[i] = swTu[n * 1312 + i];
  __syncthreads();
  const unsigned short* s_w = (const unsigned short*)s_wu;

  v2f a01 = {0.f, 0.f}, a23 = {0.f, 0.f};
  const int chb = lane * 8;          // byte offset of this lane's 4 channels
  const int g = lane >> 3;
  const unsigned char* fb = (const unsigned char*)featT;
  const unsigned short* wrow = &s_w[g * 328];
  for (int pc = wave; pc < 78; pc += 4) {
    const int p = pc / 6, c = pc - p * 6;
    const int sb = c * 52 + p;
    const int4* tb = (const int4*)tbl + (size_t)(n * 312 + pc * 4) * 2;
#pragma unroll
    for (int l4 = 0; l4 < 4; ++l4) {
      const int4 o = tb[l4 * 2];                       // uniform 16B load
      const float4 bw = ((const float4*)tb)[l4 * 2 + 1];  // uniform 16B load
      const float wg = bf2f(wrow[sb + l4 * 13]);
      const uint2 u0 = *(const uint2*)(fb + (o.x + chb));
      const uint2 u1 = *(const uint2*)(fb + (o.y + chb));
      const uint2 u2 = *(const uint2*)(fb + (o.z + chb));
      const uint2 u3 = *(const uint2*)(fb + (o.w + chb));
      const float w0 = bw.x * wg, w1 = bw.y * wg, w2 = bw.z * wg, w3 = bw.w * wg;
      v2f p0, p1, p2, p3, q0, q1, q2, q3;
      p0.x = __uint_as_float(u0.x << 16); p0.y = __uint_as_float(u0.x);
      q0.x = __uint_as_float(u0.y << 16); q0.y = __uint_as_float(u0.y);
      p1.x = __uint_as_float(u1.x << 16); p1.y = __uint_as_float(u1.x);
      q1.x = __uint_as_float(u1.y << 16); q1.y = __uint_as_float(u1.y);
      p2.x = __uint_as_float(u2.x << 16); p2.y = __uint_as_float(u2.x);
      q2.x = __uint_as_float(u2.y << 16); q2.y = __uint_as_float(u2.y);
      p3.x = __uint_as_float(u3.x << 16); p3.y = __uint_as_float(u3.x);
      q3.x = __uint_as_float(u3.y << 16); q3.y = __uint_as_float(u3.y);
      a01 += p0 * w0; a23 += q0 * w0;
      a01 += p1 * w1; a23 += q1 * w1;
      a01 += p2 * w2; a23 += q2 * w2;
      a01 += p3 * w3; a23 += q3 * w3;
    }
  }
  const int ch4 = lane * 4;
  *(float4*)&s_red[wave][ch4] = make_float4(a01.x, a01.y, a23.x, a23.y);
  __syncthreads();
  if (wave == 0) {
    float4 r = make_float4(0.f, 0.f, 0.f, 0.f);
#pragma unroll
    for (int w2 = 0; w2 < 4; ++w2) {
      const float4 t = *(const float4*)&s_red[w2][ch4];
      r.x += t.x; r.y += t.y; r.z += t.z; r.w += t.w;
    }
    uint2 o;
    o.x = f2bf(r.x) | (f2bf(r.y) << 16);
    o.y = f2bf(r.z) | (f2bf(r.w) << 16);
    *(uint2*)&featsB[n * 256 + ch4] = o;
  }
}

// MFMA GEMM: out = featsB(4096x256) @ Wob^T + b_out + resid. grid (4,64)
__global__ __launch_bounds__(256) void k_out_mfma(
    const unsigned short* __restrict__ Ab, const unsigned short* __restrict__ Bb,
    const float* __restrict__ bias, const float* __restrict__ resid,
    float* __restrict__ out) {
  const int tid = threadIdx.x;
  const int w = tid >> 6, lane = tid & 63;
  const int ml = lane & 15, q = lane >> 4;
  const int n0 = blockIdx.x * 64;
  const int m0 = blockIdx.y * 64;
  f32x4 acc[4] = {{0.f, 0.f, 0.f, 0.f}, {0.f, 0.f, 0.f, 0.f},
                  {0.f, 0.f, 0.f, 0.f}, {0.f, 0.f, 0.f, 0.f}};
  const unsigned short* Ap = Ab + (m0 + w * 16 + ml) * 256 + q * 8;
  const unsigned short* Bp = Bb + (n0 + ml) * 256 + q * 8;
#pragma unroll
  for (int kk = 0; kk < 8; ++kk) {
    const bf16x8 a = *(const bf16x8*)(Ap + kk * 32);
#pragma unroll
    for (int nt = 0; nt < 4; ++nt) {
      const bf16x8 b = *(const bf16x8*)(Bp + nt * 16 * 256 + kk * 32);
      acc[nt] = __builtin_amdgcn_mfma_f32_16x16x32_bf16(a, b, acc[nt], 0, 0, 0);
    }
  }
  const int rowb = m0 + w * 16 + q * 4;
#pragma unroll
  for (int nt = 0; nt < 4; ++nt) {
    const int col = n0 + nt * 16 + ml;
    const float b = bias[col];
#pragma unroll
    for (int r = 0; r < 4; ++r) {
      const int row = rowb + r;
      out[row * 256 + col] = acc[nt][r] + b + resid[row * 256 + col];
    }
  }
}

extern "C" void kernel_launch(void* const* d_in, const int* in_sizes, int n_in,
                              void* d_out, int out_size, void* d_ws, size_t ws_size,
                              hipStream_t stream) {
  (void)in_sizes; (void)n_in; (void)out_size; (void)ws_size;
  const float* iw      = (const float*)d_in[1];
  const float* anchor  = (const float*)d_in[2];
  const float* f0      = (const float*)d_in[3];
  const float* f1      = (const float*)d_in[4];
  const float* f2      = (const float*)d_in[5];
  const float* f3      = (const float*)d_in[6];
  const float* proj    = (const float*)d_in[7];
  const float* wh      = (const float*)d_in[8];
  const float* W_learn = (const float*)d_in[9];
  const float* b_learn = (const float*)d_in[10];
  const float* W_wts   = (const float*)d_in[11];
  const float* b_wts   = (const float*)d_in[12];
  const float* W_out   = (const float*)d_in[13];
  const float* b_out   = (const float*)d_in[14];
  float* out = (float*)d_out;
  float* ws = (float*)d_ws;
  unsigned short* featT   = (unsigned short*)ws;
  unsigned short* logitsB = (unsigned short*)(ws + WS_LOGB);
  unsigned short* featsB  = (unsigned short*)(ws + WS_FEATB);
  float*          learn   = ws + WS_LEARN;
  unsigned short* Ab      = (unsigned short*)(ws + WS_AB);
  unsigned short* Bb      = (unsigned short*)(ws + WS_BB);
  unsigned short* Wob     = (unsigned short*)(ws + WS_WOB);
  unsigned int*   swTu    = (unsigned int*)(ws + WS_SWT);
  int*            tbl     = (int*)(ws + WS_TBL);

  k_transpose_all<<<dim3(12, 64, 48), 256, 0, stream>>>(f0, f1, f2, f3, featT);
  k_prep_pack<<<1728, 256, 0, stream>>>(iw, W_wts, W_learn, W_out, Ab, Bb, Wob);
  k_wts_mfma<<<dim3(40, 64), 256, 0, stream>>>(Ab, Bb, b_wts, b_learn, logitsB, learn);
  k_prep_tables<<<4096, 256, 0, stream>>>(anchor, logitsB, learn, proj, wh, swTu, tbl);
  k_gather<<<4096, 256, 0, stream>>>(swTu, tbl, featT, featsB);
  k_out_mfma<<<dim3(4, 64), 256, 0, stream>>>(featsB, Wob, b_out, iw, out);
}

// Round 7
// 331.293 us; speedup vs baseline: 1.4515x; 1.4515x over previous
//
#include <hip/hip_runtime.h>
#include <math.h>

// ---------------------------------------------------------------------------
// DeformableFeatureAggregation — MI355X
// Pipeline (5 launches):
//   k_transpose_all : feat L0..L3 (6,256,H,W) fp32 -> featF (6,H,W,256) fp8 e4m3
//   k_prep_pack     : iw->Ab bf16 ; [W_wts|W_learn]->Bb bf16 N-major ; W_out->Wob
//   k_wts_mfma      : MFMA -> logitsB bf16 (4096x2496) + learn fp32 (4096x18)
//   k_sample        : FUSED per-anchor block: task-ordered softmax (LDS),
//                     projection, task tables (LDS), fp8 bilinear gather
//                     -> featsB bf16
//   k_out_mfma      : MFMA out = featsB @ W_out^T + b_out + iw (fp32)
// Workspace (float offsets):
//   featF  : bytes 0..22978560                (f 0..5744640)
//   logitsB: f 5744640   (4096x2496 ush)  -> 10856448
//   featsB : f 10856448  (4096x256 ush)   -> 11380736
//   learn  : f 11380736  (4096x18 f)      -> 11454464
//   Ab     : f 11454464  (4096x256 ush)   -> 11978752
//   Bb     : f 11978752  (2560x256 ush)   -> 12306432
//   Wob    : f 12306432  (256x256 ush)    -> 12339200   (~49 MB)
// ---------------------------------------------------------------------------

#define FT_L0 0
#define FT_L1 17301504
#define FT_L2 21626880
#define FT_L3 22708224
#define WS_LOGB 5744640
#define WS_FEATB 10856448
#define WS_LEARN 11380736
#define WS_AB 11454464
#define WS_BB 11978752
#define WS_WOB 12306432

typedef float v2f __attribute__((ext_vector_type(2)));
typedef __attribute__((ext_vector_type(8))) short bf16x8;
typedef __attribute__((ext_vector_type(4))) float f32x4;

__device__ const float FIXS[7][3] = {
    {0.f, 0.f, 0.f},  {0.45f, 0.f, 0.f}, {-0.45f, 0.f, 0.f}, {0.f, 0.45f, 0.f},
    {0.f, -0.45f, 0.f}, {0.f, 0.f, 0.45f}, {0.f, 0.f, -0.45f}};

__device__ __forceinline__ unsigned int f2bf(float f) {
  unsigned int u = __float_as_uint(f);
  u += 0x7fffu + ((u >> 16) & 1u);  // RTNE
  return u >> 16;
}
__device__ __forceinline__ float bf2f(unsigned short u) {
  return __uint_as_float(((unsigned int)u) << 16);
}

// All 4 levels: (6,256,H,W) fp32 -> (6,H,W,256) fp8 e4m3. grid (12, 64, 48)
__global__ __launch_bounds__(256) void k_transpose_all(
    const float* __restrict__ f0, const float* __restrict__ f1,
    const float* __restrict__ f2, const float* __restrict__ f3,
    unsigned char* __restrict__ featF) {
  const int bx = blockIdx.x;
  const float* src;
  unsigned char* dst;
  int H, W, xt;
  if (bx < 6)       { src = f0; dst = featF + FT_L0; H = 64; W = 176; xt = bx * 32; }
  else if (bx < 9)  { src = f1; dst = featF + FT_L1; H = 32; W = 88;  xt = (bx - 6) * 32; }
  else if (bx < 11) { src = f2; dst = featF + FT_L2; H = 16; W = 44;  xt = (bx - 9) * 32; }
  else              { src = f3; dst = featF + FT_L3; H = 8;  W = 22;  xt = 0; }
  const int y = blockIdx.y;
  if (y >= H) return;
  __shared__ float tile[32][33];
  const int tid = threadIdx.x;
  const int i = tid & 31;
  const int j = tid >> 5;
  const int c = blockIdx.z >> 3;
  const int cht = (blockIdx.z & 7) * 32;
#pragma unroll
  for (int jj = j; jj < 32; jj += 8) {
    int x = xt + i;
    float v = 0.f;
    if (x < W) v = src[((c * 256 + cht + jj) * H + y) * W + x];
    tile[jj][i] = v;
  }
  __syncthreads();
  // write: thread -> (x = xt + tid>>3, channel quad q = tid&7); 4 fp8 per u32
  const int q = tid & 7;
  const int xw = tid >> 3;
  const int x = xt + xw;
  if (x < W) {
    const float v0 = tile[q * 4 + 0][xw];
    const float v1 = tile[q * 4 + 1][xw];
    const float v2 = tile[q * 4 + 2][xw];
    const float v3 = tile[q * 4 + 3][xw];
    int pk = __builtin_amdgcn_cvt_pk_fp8_f32(v0, v1, 0, false);
    pk = __builtin_amdgcn_cvt_pk_fp8_f32(v2, v3, pk, true);
    *(unsigned int*)(dst + (((c * H + y) * W + x) * 256) + cht + q * 4) =
        (unsigned int)pk;
  }
}

// Fused packing: bx<1024 -> Ab ; <1664 -> Bb tile ; else Wob tile. grid 1728.
__global__ __launch_bounds__(256) void k_prep_pack(
    const float* __restrict__ iw, const float* __restrict__ Ww,
    const float* __restrict__ Wl, const float* __restrict__ Wo,
    unsigned short* __restrict__ Ab, unsigned short* __restrict__ Bb,
    unsigned short* __restrict__ Wob) {
  __shared__ unsigned short tile[32][33];
  const int tid = threadIdx.x;
  const int bx = blockIdx.x;
  if (bx < 1024) {
    const int i = bx * 256 + tid;
    const float4 v = ((const float4*)iw)[i];
    uint2 o;
    o.x = f2bf(v.x) | (f2bf(v.y) << 16);
    o.y = f2bf(v.z) | (f2bf(v.w) << 16);
    ((uint2*)Ab)[i] = o;
    return;
  }
  const int i = tid & 31;
  const int r = tid >> 5;
  if (bx < 1664) {
    const int idx = bx - 1024;
    const int j0 = (idx % 80) * 32;
    const int k0 = (idx / 80) * 32;
#pragma unroll
    for (int rr = r; rr < 32; rr += 8) {
      const int k = k0 + rr, j = j0 + i;
      float v = 0.f;
      if (j < 2496) v = Ww[k * 2496 + j];
      else if (j < 2514) v = Wl[k * 18 + (j - 2496)];
      tile[rr][i] = (unsigned short)f2bf(v);
    }
    __syncthreads();
#pragma unroll
    for (int rr = r; rr < 32; rr += 8)
      Bb[(j0 + rr) * 256 + k0 + i] = tile[i][rr];
  } else {
    const int idx = bx - 1664;
    const int j0 = (idx & 7) * 32;
    const int k0 = (idx >> 3) * 32;
#pragma unroll
    for (int rr = r; rr < 32; rr += 8)
      tile[rr][i] = (unsigned short)f2bf(Wo[(k0 + rr) * 256 + j0 + i]);
    __syncthreads();
#pragma unroll
    for (int rr = r; rr < 32; rr += 8)
      Wob[(j0 + rr) * 256 + k0 + i] = tile[i][rr];
  }
}

// MFMA GEMM: [logits | learn] = Ab(4096x256) @ Bb^T + bias. grid (40,64)
__global__ __launch_bounds__(256) void k_wts_mfma(
    const unsigned short* __restrict__ Ab, const unsigned short* __restrict__ Bb,
    const float* __restrict__ b_wts, const float* __restrict__ b_learn,
    unsigned short* __restrict__ logitsB, float* __restrict__ learn) {
  const int tid = threadIdx.x;
  const int w = tid >> 6, lane = tid & 63;
  const int ml = lane & 15, q = lane >> 4;
  const int n0 = blockIdx.x * 64;
  const int m0 = blockIdx.y * 64;
  f32x4 acc[4] = {{0.f, 0.f, 0.f, 0.f}, {0.f, 0.f, 0.f, 0.f},
                  {0.f, 0.f, 0.f, 0.f}, {0.f, 0.f, 0.f, 0.f}};
  const unsigned short* Ap = Ab + (m0 + w * 16 + ml) * 256 + q * 8;
  const unsigned short* Bp = Bb + (n0 + ml) * 256 + q * 8;
#pragma unroll
  for (int kk = 0; kk < 8; ++kk) {
    const bf16x8 a = *(const bf16x8*)(Ap + kk * 32);
#pragma unroll
    for (int nt = 0; nt < 4; ++nt) {
      const bf16x8 b = *(const bf16x8*)(Bp + nt * 16 * 256 + kk * 32);
      acc[nt] = __builtin_amdgcn_mfma_f32_16x16x32_bf16(a, b, acc[nt], 0, 0, 0);
    }
  }
  const int rowb = m0 + w * 16 + q * 4;
#pragma unroll
  for (int nt = 0; nt < 4; ++nt) {
    const int col = n0 + nt * 16 + ml;
    if (col < 2496) {
      const float b = b_wts[col];
#pragma unroll
      for (int r = 0; r < 4; ++r)
        logitsB[(rowb + r) * 2496 + col] = (unsigned short)f2bf(acc[nt][r] + b);
    } else if (col < 2514) {
      const float b = b_learn[col - 2496];
#pragma unroll
      for (int r = 0; r < 4; ++r) {
        float v = fminf(fmaxf(acc[nt][r] + b, -9.21f), 9.21f);
        learn[(rowb + r) * 18 + (col - 2496)] = 1.f / (1.f + expf(-v)) - 0.5f;
      }
    }
  }
}

// Fused per-anchor sampler. grid 4096 x 256.
__global__ __launch_bounds__(256, 6) void k_sample(
    const float* __restrict__ anchor, const unsigned short* __restrict__ logitsB,
    const float* __restrict__ learn_g, const unsigned char* __restrict__ featF,
    const float* __restrict__ proj, const float* __restrict__ wh,
    unsigned short* __restrict__ featsB) {
  const int n = blockIdx.x;
  const int tid = threadIdx.x;
  const int lane = tid & 63;
  const int wave = tid >> 6;
  __shared__ unsigned short s_w[8 * 320];  // bf16 softmax weights [g][t], t=pc*4+l
  __shared__ float s_p2d[78][2];
  __shared__ float s_learn[18];
  __shared__ int4 s_off[312];    // corner BYTE offsets per task t
  __shared__ float4 s_wt[312];   // bilinear corner weights per task t
  __shared__ float s_red[4][256];

  // phase 1: logits -> LDS, permuted to task order t=(p*6+c)*4+l from
  // s = c*52 + l*13 + p (softmax is order-invariant over the 312 axis)
  for (int i = tid; i < 2496; i += 256) {
    const int s = i >> 3, g = i & 7;
    const int c = s / 52;
    const int r = s - c * 52;
    const int l = r / 13;
    const int p = r - l * 13;
    s_w[g * 320 + (p * 6 + c) * 4 + l] = logitsB[n * 2496 + i];
  }
  if (tid < 18) s_learn[tid] = learn_g[n * 18 + tid];
  __syncthreads();

  // phase 2: softmax over the 312 tasks per group; wave w -> groups 2w, 2w+1
#pragma unroll
  for (int gg = 0; gg < 2; ++gg) {
    unsigned short* row = &s_w[(wave * 2 + gg) * 320];
    float l[5];
    float mx = -1e30f;
#pragma unroll
    for (int i = 0; i < 5; ++i) {
      const int s = lane + i * 64;
      l[i] = (s < 312) ? bf2f(row[s]) : -1e30f;
      mx = fmaxf(mx, l[i]);
    }
    for (int off = 32; off; off >>= 1) mx = fmaxf(mx, __shfl_xor(mx, off));
    float sum = 0.f;
#pragma unroll
    for (int i = 0; i < 5; ++i) {
      l[i] = __expf(l[i] - mx);
      sum += l[i];
    }
    for (int off = 32; off; off >>= 1) sum += __shfl_xor(sum, off);
    const float inv = 1.f / sum;
#pragma unroll
    for (int i = 0; i < 5; ++i) {
      const int s = lane + i * 64;
      if (s < 312) row[s] = (unsigned short)f2bf(l[i] * inv);
    }
  }

  // phase 3: projection of 78 (pt,cam) pairs
  if (tid < 78) {
    const int p = tid / 6, c = tid % 6;
    const float* an = anchor + n * 11;
    float qw = an[6], qx = an[7], qy = an[8], qz = an[9];
    const float qinv = 1.f / sqrtf(qw * qw + qx * qx + qy * qy + qz * qz);
    qw *= qinv; qx *= qinv; qy *= qinv; qz *= qinv;
    const float R00 = 1.f - 2.f * (qy * qy + qz * qz), R01 = 2.f * (qx * qy - qw * qz), R02 = 2.f * (qx * qz + qw * qy);
    const float R10 = 2.f * (qx * qy + qw * qz), R11 = 1.f - 2.f * (qx * qx + qz * qz), R12 = 2.f * (qy * qz - qw * qx);
    const float R20 = 2.f * (qx * qz - qw * qy), R21 = 2.f * (qy * qz + qw * qx), R22 = 1.f - 2.f * (qx * qx + qy * qy);
    float s0, s1, s2;
    if (p < 7) {
      s0 = FIXS[p][0]; s1 = FIXS[p][1]; s2 = FIXS[p][2];
    } else {
      const int b = (p - 7) * 3;
      s0 = s_learn[b]; s1 = s_learn[b + 1]; s2 = s_learn[b + 2];
    }
    const float vx = s0 * an[3], vy = s1 * an[4], vz = s2 * an[5];
    const float kx = R00 * vx + R10 * vy + R20 * vz + an[0];
    const float ky = R01 * vx + R11 * vy + R21 * vz + an[1];
    const float kz = R02 * vx + R12 * vy + R22 * vz + an[2];
    const float* P = proj + c * 16;
    const float h0 = P[0] * kx + P[1] * ky + P[2] * kz + P[3];
    const float h1 = P[4] * kx + P[5] * ky + P[6] * kz + P[7];
    const float h2 = P[8] * kx + P[9] * ky + P[10] * kz + P[11];
    const float zz = fmaxf(h2, 1e-5f);
    float px = h0 / zz / wh[c * 2 + 0];
    float py = h1 / zz / wh[c * 2 + 1];
    px = fminf(fmaxf(px, 0.f), 0.9999f);
    py = fminf(fmaxf(py, 0.f), 0.9999f);
    s_p2d[tid][0] = px;
    s_p2d[tid][1] = py;
  }
  __syncthreads();

  // phase 4: per-task corner BYTE offsets (fp8 layout) + bilinear weights
  {
    constexpr int LBB[4] = {FT_L0, FT_L1, FT_L2, FT_L3};                 // bytes
    constexpr int CSB[4] = {2883584, 720896, 180224, 45056};             // H*W*256
    for (int t = tid; t < 312; t += 256) {
      const int pc = t >> 2, l = t & 3;
      const int c = pc % 6;
      const int H = 64 >> l, W = 176 >> l;
      const float fx = s_p2d[pc][0] * (float)W - 0.5f;
      const float fy = s_p2d[pc][1] * (float)H - 0.5f;
      const float x0f = floorf(fx), y0f = floorf(fy);
      const float wx = fx - x0f, wy = fy - y0f;
      const int x0 = (int)x0f, y0 = (int)y0f;
      const float mx0 = (x0 >= 0) ? 1.f : 0.f;
      const float mx1 = (x0 + 1 < W) ? 1.f : 0.f;
      const float my0 = (y0 >= 0) ? 1.f : 0.f;
      const float my1 = (y0 + 1 < H) ? 1.f : 0.f;
      const int cx0 = max(x0, 0), cx1 = min(x0 + 1, W - 1);
      const int cy0 = max(y0, 0), cy1 = min(y0 + 1, H - 1);
      const int base = LBB[l] + c * CSB[l];
      int4 o;
      o.x = base + (cy0 * W + cx0) * 256;
      o.y = base + (cy0 * W + cx1) * 256;
      o.z = base + (cy1 * W + cx0) * 256;
      o.w = base + (cy1 * W + cx1) * 256;
      s_off[t] = o;
      float4 w4;
      w4.x = (1.f - wx) * (1.f - wy) * mx0 * my0;
      w4.y = wx * (1.f - wy) * mx1 * my0;
      w4.z = (1.f - wx) * wy * mx0 * my1;
      w4.w = wx * wy * mx1 * my1;
      s_wt[t] = w4;
    }
  }
  __syncthreads();

  // phase 5: fp8 gather. wave handles pc = wave, wave+4, ...
  float4 acc = make_float4(0.f, 0.f, 0.f, 0.f);
  const int chb = lane * 4;   // byte offset of this lane's 4 fp8 channels
  const int g = lane >> 3;
  const unsigned short* wrow = &s_w[g * 320];
  for (int pc = wave; pc < 78; pc += 4) {
    const int t0 = pc * 4;
    const uint2 wq = *(const uint2*)&wrow[t0];  // 4 bf16 level-weights, 1 b64
    float wgl[4];
    wgl[0] = __uint_as_float(wq.x << 16);
    wgl[1] = __uint_as_float(wq.x & 0xffff0000u);
    wgl[2] = __uint_as_float(wq.y << 16);
    wgl[3] = __uint_as_float(wq.y & 0xffff0000u);
#pragma unroll
    for (int l4 = 0; l4 < 4; ++l4) {
      const int4 o = s_off[t0 + l4];
      const float4 bw = s_wt[t0 + l4];
      const float wg = wgl[l4];
      const unsigned int u0 = *(const unsigned int*)(featF + (o.x + chb));
      const unsigned int u1 = *(const unsigned int*)(featF + (o.y + chb));
      const unsigned int u2 = *(const unsigned int*)(featF + (o.z + chb));
      const unsigned int u3 = *(const unsigned int*)(featF + (o.w + chb));
      const float w0 = bw.x * wg, w1 = bw.y * wg, w2 = bw.z * wg, w3 = bw.w * wg;
      const v2f lo0 = __builtin_amdgcn_cvt_pk_f32_fp8((int)u0, false);
      const v2f hi0 = __builtin_amdgcn_cvt_pk_f32_fp8((int)u0, true);
      const v2f lo1 = __builtin_amdgcn_cvt_pk_f32_fp8((int)u1, false);
      const v2f hi1 = __builtin_amdgcn_cvt_pk_f32_fp8((int)u1, true);
      const v2f lo2 = __builtin_amdgcn_cvt_pk_f32_fp8((int)u2, false);
      const v2f hi2 = __builtin_amdgcn_cvt_pk_f32_fp8((int)u2, true);
      const v2f lo3 = __builtin_amdgcn_cvt_pk_f32_fp8((int)u3, false);
      const v2f hi3 = __builtin_amdgcn_cvt_pk_f32_fp8((int)u3, true);
      acc.x += lo0.x * w0 + lo1.x * w1 + lo2.x * w2 + lo3.x * w3;
      acc.y += lo0.y * w0 + lo1.y * w1 + lo2.y * w2 + lo3.y * w3;
      acc.z += hi0.x * w0 + hi1.x * w1 + hi2.x * w2 + hi3.x * w3;
      acc.w += hi0.y * w0 + hi1.y * w1 + hi2.y * w2 + hi3.y * w3;
    }
  }
  const int ch4 = lane * 4;
  *(float4*)&s_red[wave][ch4] = acc;
  __syncthreads();
  if (wave == 0) {
    float4 r = make_float4(0.f, 0.f, 0.f, 0.f);
#pragma unroll
    for (int w2 = 0; w2 < 4; ++w2) {
      const float4 t = *(const float4*)&s_red[w2][ch4];
      r.x += t.x; r.y += t.y; r.z += t.z; r.w += t.w;
    }
    uint2 o;
    o.x = f2bf(r.x) | (f2bf(r.y) << 16);
    o.y = f2bf(r.z) | (f2bf(r.w) << 16);
    *(uint2*)&featsB[n * 256 + ch4] = o;
  }
}

// MFMA GEMM: out = featsB(4096x256) @ Wob^T + b_out + resid. grid (4,64)
__global__ __launch_bounds__(256) void k_out_mfma(
    const unsigned short* __restrict__ Ab, const unsigned short* __restrict__ Bb,
    const float* __restrict__ bias, const float* __restrict__ resid,
    float* __restrict__ out) {
  const int tid = threadIdx.x;
  const int w = tid >> 6, lane = tid & 63;
  const int ml = lane & 15, q = lane >> 4;
  const int n0 = blockIdx.x * 64;
  const int m0 = blockIdx.y * 64;
  f32x4 acc[4] = {{0.f, 0.f, 0.f, 0.f}, {0.f, 0.f, 0.f, 0.f},
                  {0.f, 0.f, 0.f, 0.f}, {0.f, 0.f, 0.f, 0.f}};
  const unsigned short* Ap = Ab + (m0 + w * 16 + ml) * 256 + q * 8;
  const unsigned short* Bp = Bb + (n0 + ml) * 256 + q * 8;
#pragma unroll
  for (int kk = 0; kk < 8; ++kk) {
    const bf16x8 a = *(const bf16x8*)(Ap + kk * 32);
#pragma unroll
    for (int nt = 0; nt < 4; ++nt) {
      const bf16x8 b = *(const bf16x8*)(Bp + nt * 16 * 256 + kk * 32);
      acc[nt] = __builtin_amdgcn_mfma_f32_16x16x32_bf16(a, b, acc[nt], 0, 0, 0);
    }
  }
  const int rowb = m0 + w * 16 + q * 4;
#pragma unroll
  for (int nt = 0; nt < 4; ++nt) {
    const int col = n0 + nt * 16 + ml;
    const float b = bias[col];
#pragma unroll
    for (int r = 0; r < 4; ++r) {
      const int row = rowb + r;
      out[row * 256 + col] = acc[nt][r] + b + resid[row * 256 + col];
    }
  }
}

extern "C" void kernel_launch(void* const* d_in, const int* in_sizes, int n_in,
                              void* d_out, int out_size, void* d_ws, size_t ws_size,
                              hipStream_t stream) {
  (void)in_sizes; (void)n_in; (void)out_size; (void)ws_size;
  const float* iw      = (const float*)d_in[1];
  const float* anchor  = (const float*)d_in[2];
  const float* f0      = (const float*)d_in[3];
  const float* f1      = (const float*)d_in[4];
  const float* f2      = (const float*)d_in[5];
  const float* f3      = (const float*)d_in[6];
  const float* proj    = (const float*)d_in[7];
  const float* wh      = (const float*)d_in[8];
  const float* W_learn = (const float*)d_in[9];
  const float* b_learn = (const float*)d_in[10];
  const float* W_wts   = (const float*)d_in[11];
  const float* b_wts   = (const float*)d_in[12];
  const float* W_out   = (const float*)d_in[13];
  const float* b_out   = (const float*)d_in[14];
  float* out = (float*)d_out;
  float* ws = (float*)d_ws;
  unsigned char*  featF   = (unsigned char*)ws;
  unsigned short* logitsB = (unsigned short*)(ws + WS_LOGB);
  unsigned short* featsB  = (unsigned short*)(ws + WS_FEATB);
  float*          learn   = ws + WS_LEARN;
  unsigned short* Ab      = (unsigned short*)(ws + WS_AB);
  unsigned short* Bb      = (unsigned short*)(ws + WS_BB);
  unsigned short* Wob     = (unsigned short*)(ws + WS_WOB);

  k_transpose_all<<<dim3(12, 64, 48), 256, 0, stream>>>(f0, f1, f2, f3, featF);
  k_prep_pack<<<1728, 256, 0, stream>>>(iw, W_wts, W_learn, W_out, Ab, Bb, Wob);
  k_wts_mfma<<<dim3(40, 64), 256, 0, stream>>>(Ab, Bb, b_wts, b_learn, logitsB, learn);
  k_sample<<<4096, 256, 0, stream>>>(anchor, logitsB, learn, featF, proj, wh, featsB);
  k_out_mfma<<<dim3(4, 64), 256, 0, stream>>>(featsB, Wob, b_out, iw, out);
}

// Round 8
// 325.977 us; speedup vs baseline: 1.4752x; 1.0163x over previous
//
#include <hip/hip_runtime.h>
#include <math.h>

// ---------------------------------------------------------------------------
// DeformableFeatureAggregation — MI355X
// Pipeline (5 launches):
//   k_transpose_all : feat L0..L3 (6,256,H,W) fp32 -> featF (6,H,W,256) fp8 e4m3
//   k_prep_pack     : iw->Ab bf16 ; [W_wts|W_learn]->Bb bf16 N-major ; W_out->Wob
//   k_wts_mfma      : MFMA -> logitsB bf16 (4096x2496) + learn fp32 (4096x18)
//   k_sample        : FUSED per-anchor block: task-ordered softmax (LDS),
//                     projection, task tables (LDS, padded to 320 tasks),
//                     fp8 gather: half-wave = one pc, 8 ch/lane, v2f pk_fma
//   k_out_mfma      : MFMA out = featsB @ W_out^T + b_out + iw (fp32)
// Workspace (float offsets):
//   featF  : bytes 0..22978560                (f 0..5744640)
//   logitsB: f 5744640   (4096x2496 ush)  -> 10856448
//   featsB : f 10856448  (4096x256 ush)   -> 11380736
//   learn  : f 11380736  (4096x18 f)      -> 11454464
//   Ab     : f 11454464  (4096x256 ush)   -> 11978752
//   Bb     : f 11978752  (2560x256 ush)   -> 12306432
//   Wob    : f 12306432  (256x256 ush)    -> 12339200   (~49 MB)
// ---------------------------------------------------------------------------

#define FT_L0 0
#define FT_L1 17301504
#define FT_L2 21626880
#define FT_L3 22708224
#define WS_LOGB 5744640
#define WS_FEATB 10856448
#define WS_LEARN 11380736
#define WS_AB 11454464
#define WS_BB 11978752
#define WS_WOB 12306432

typedef float v2f __attribute__((ext_vector_type(2)));
typedef __attribute__((ext_vector_type(8))) short bf16x8;
typedef __attribute__((ext_vector_type(4))) float f32x4;

__device__ const float FIXS[7][3] = {
    {0.f, 0.f, 0.f},  {0.45f, 0.f, 0.f}, {-0.45f, 0.f, 0.f}, {0.f, 0.45f, 0.f},
    {0.f, -0.45f, 0.f}, {0.f, 0.f, 0.45f}, {0.f, 0.f, -0.45f}};

__device__ __forceinline__ unsigned int f2bf(float f) {
  unsigned int u = __float_as_uint(f);
  u += 0x7fffu + ((u >> 16) & 1u);  // RTNE
  return u >> 16;
}
__device__ __forceinline__ float bf2f(unsigned short u) {
  return __uint_as_float(((unsigned int)u) << 16);
}

// All 4 levels: (6,256,H,W) fp32 -> (6,H,W,256) fp8 e4m3. grid (12, 64, 48)
__global__ __launch_bounds__(256) void k_transpose_all(
    const float* __restrict__ f0, const float* __restrict__ f1,
    const float* __restrict__ f2, const float* __restrict__ f3,
    unsigned char* __restrict__ featF) {
  const int bx = blockIdx.x;
  const float* src;
  unsigned char* dst;
  int H, W, xt;
  if (bx < 6)       { src = f0; dst = featF + FT_L0; H = 64; W = 176; xt = bx * 32; }
  else if (bx < 9)  { src = f1; dst = featF + FT_L1; H = 32; W = 88;  xt = (bx - 6) * 32; }
  else if (bx < 11) { src = f2; dst = featF + FT_L2; H = 16; W = 44;  xt = (bx - 9) * 32; }
  else              { src = f3; dst = featF + FT_L3; H = 8;  W = 22;  xt = 0; }
  const int y = blockIdx.y;
  if (y >= H) return;
  __shared__ float tile[32][33];
  const int tid = threadIdx.x;
  const int i = tid & 31;
  const int j = tid >> 5;
  const int c = blockIdx.z >> 3;
  const int cht = (blockIdx.z & 7) * 32;
#pragma unroll
  for (int jj = j; jj < 32; jj += 8) {
    int x = xt + i;
    float v = 0.f;
    if (x < W) v = src[((c * 256 + cht + jj) * H + y) * W + x];
    tile[jj][i] = v;
  }
  __syncthreads();
  // write: thread -> (x = xt + tid>>3, channel quad q = tid&7); 4 fp8 per u32
  const int q = tid & 7;
  const int xw = tid >> 3;
  const int x = xt + xw;
  if (x < W) {
    const float v0 = tile[q * 4 + 0][xw];
    const float v1 = tile[q * 4 + 1][xw];
    const float v2 = tile[q * 4 + 2][xw];
    const float v3 = tile[q * 4 + 3][xw];
    int pk = __builtin_amdgcn_cvt_pk_fp8_f32(v0, v1, 0, false);
    pk = __builtin_amdgcn_cvt_pk_fp8_f32(v2, v3, pk, true);
    *(unsigned int*)(dst + (((c * H + y) * W + x) * 256) + cht + q * 4) =
        (unsigned int)pk;
  }
}

// Fused packing: bx<1024 -> Ab ; <1664 -> Bb tile ; else Wob tile. grid 1728.
__global__ __launch_bounds__(256) void k_prep_pack(
    const float* __restrict__ iw, const float* __restrict__ Ww,
    const float* __restrict__ Wl, const float* __restrict__ Wo,
    unsigned short* __restrict__ Ab, unsigned short* __restrict__ Bb,
    unsigned short* __restrict__ Wob) {
  __shared__ unsigned short tile[32][33];
  const int tid = threadIdx.x;
  const int bx = blockIdx.x;
  if (bx < 1024) {
    const int i = bx * 256 + tid;
    const float4 v = ((const float4*)iw)[i];
    uint2 o;
    o.x = f2bf(v.x) | (f2bf(v.y) << 16);
    o.y = f2bf(v.z) | (f2bf(v.w) << 16);
    ((uint2*)Ab)[i] = o;
    return;
  }
  const int i = tid & 31;
  const int r = tid >> 5;
  if (bx < 1664) {
    const int idx = bx - 1024;
    const int j0 = (idx % 80) * 32;
    const int k0 = (idx / 80) * 32;
#pragma unroll
    for (int rr = r; rr < 32; rr += 8) {
      const int k = k0 + rr, j = j0 + i;
      float v = 0.f;
      if (j < 2496) v = Ww[k * 2496 + j];
      else if (j < 2514) v = Wl[k * 18 + (j - 2496)];
      tile[rr][i] = (unsigned short)f2bf(v);
    }
    __syncthreads();
#pragma unroll
    for (int rr = r; rr < 32; rr += 8)
      Bb[(j0 + rr) * 256 + k0 + i] = tile[i][rr];
  } else {
    const int idx = bx - 1664;
    const int j0 = (idx & 7) * 32;
    const int k0 = (idx >> 3) * 32;
#pragma unroll
    for (int rr = r; rr < 32; rr += 8)
      tile[rr][i] = (unsigned short)f2bf(Wo[(k0 + rr) * 256 + j0 + i]);
    __syncthreads();
#pragma unroll
    for (int rr = r; rr < 32; rr += 8)
      Wob[(j0 + rr) * 256 + k0 + i] = tile[i][rr];
  }
}

// MFMA GEMM: [logits | learn] = Ab(4096x256) @ Bb^T + bias. grid (40,64)
__global__ __launch_bounds__(256) void k_wts_mfma(
    const unsigned short* __restrict__ Ab, const unsigned short* __restrict__ Bb,
    const float* __restrict__ b_wts, const float* __restrict__ b_learn,
    unsigned short* __restrict__ logitsB, float* __restrict__ learn) {
  const int tid = threadIdx.x;
  const int w = tid >> 6, lane = tid & 63;
  const int ml = lane & 15, q = lane >> 4;
  const int n0 = blockIdx.x * 64;
  const int m0 = blockIdx.y * 64;
  f32x4 acc[4] = {{0.f, 0.f, 0.f, 0.f}, {0.f, 0.f, 0.f, 0.f},
                  {0.f, 0.f, 0.f, 0.f}, {0.f, 0.f, 0.f, 0.f}};
  const unsigned short* Ap = Ab + (m0 + w * 16 + ml) * 256 + q * 8;
  const unsigned short* Bp = Bb + (n0 + ml) * 256 + q * 8;
#pragma unroll
  for (int kk = 0; kk < 8; ++kk) {
    const bf16x8 a = *(const bf16x8*)(Ap + kk * 32);
#pragma unroll
    for (int nt = 0; nt < 4; ++nt) {
      const bf16x8 b = *(const bf16x8*)(Bp + nt * 16 * 256 + kk * 32);
      acc[nt] = __builtin_amdgcn_mfma_f32_16x16x32_bf16(a, b, acc[nt], 0, 0, 0);
    }
  }
  const int rowb = m0 + w * 16 + q * 4;
#pragma unroll
  for (int nt = 0; nt < 4; ++nt) {
    const int col = n0 + nt * 16 + ml;
    if (col < 2496) {
      const float b = b_wts[col];
#pragma unroll
      for (int r = 0; r < 4; ++r)
        logitsB[(rowb + r) * 2496 + col] = (unsigned short)f2bf(acc[nt][r] + b);
    } else if (col < 2514) {
      const float b = b_learn[col - 2496];
#pragma unroll
      for (int r = 0; r < 4; ++r) {
        float v = fminf(fmaxf(acc[nt][r] + b, -9.21f), 9.21f);
        learn[(rowb + r) * 18 + (col - 2496)] = 1.f / (1.f + expf(-v)) - 0.5f;
      }
    }
  }
}

// Fused per-anchor sampler. grid 4096 x 256.
// phase 5: half-wave = one pc (32 lanes x 8 channels), v2f pk_fma blend.
__global__ __launch_bounds__(256, 6) void k_sample(
    const float* __restrict__ anchor, const unsigned short* __restrict__ logitsB,
    const float* __restrict__ learn_g, const unsigned char* __restrict__ featF,
    const float* __restrict__ proj, const float* __restrict__ wh,
    unsigned short* __restrict__ featsB) {
  const int n = blockIdx.x;
  const int tid = threadIdx.x;
  const int lane = tid & 63;
  const int wave = tid >> 6;
  __shared__ unsigned short s_w[8 * 328];  // bf16 softmax weights [g][t], pad 328
  __shared__ float s_p2d[78][2];
  __shared__ float s_learn[18];
  __shared__ int4 s_off[320];    // corner BYTE offsets per task t (pad to 320)
  __shared__ float4 s_wt[320];   // bilinear corner weights per task t
  __shared__ float s_red[8][256];

  // phase 1: logits -> LDS, permuted to task order t=(p*6+c)*4+l from
  // s = c*52 + l*13 + p (softmax is order-invariant over the 312 axis)
  for (int i = tid; i < 2496; i += 256) {
    const int s = i >> 3, g = i & 7;
    const int c = s / 52;
    const int r = s - c * 52;
    const int l = r / 13;
    const int p = r - l * 13;
    s_w[g * 328 + (p * 6 + c) * 4 + l] = logitsB[n * 2496 + i];
  }
  if (tid < 64) s_w[(tid >> 3) * 328 + 312 + (tid & 7)] = 0;  // zero pad tasks
  if (tid < 18) s_learn[tid] = learn_g[n * 18 + tid];
  __syncthreads();

  // phase 2: softmax over the 312 tasks per group; wave w -> groups 2w, 2w+1
#pragma unroll
  for (int gg = 0; gg < 2; ++gg) {
    unsigned short* row = &s_w[(wave * 2 + gg) * 328];
    float l[5];
    float mx = -1e30f;
#pragma unroll
    for (int i = 0; i < 5; ++i) {
      const int s = lane + i * 64;
      l[i] = (s < 312) ? bf2f(row[s]) : -1e30f;
      mx = fmaxf(mx, l[i]);
    }
    for (int off = 32; off; off >>= 1) mx = fmaxf(mx, __shfl_xor(mx, off));
    float sum = 0.f;
#pragma unroll
    for (int i = 0; i < 5; ++i) {
      l[i] = __expf(l[i] - mx);
      sum += l[i];
    }
    for (int off = 32; off; off >>= 1) sum += __shfl_xor(sum, off);
    const float inv = 1.f / sum;
#pragma unroll
    for (int i = 0; i < 5; ++i) {
      const int s = lane + i * 64;
      if (s < 312) row[s] = (unsigned short)f2bf(l[i] * inv);
    }
  }

  // phase 3: projection of 78 (pt,cam) pairs
  if (tid < 78) {
    const int p = tid / 6, c = tid % 6;
    const float* an = anchor + n * 11;
    float qw = an[6], qx = an[7], qy = an[8], qz = an[9];
    const float qinv = 1.f / sqrtf(qw * qw + qx * qx + qy * qy + qz * qz);
    qw *= qinv; qx *= qinv; qy *= qinv; qz *= qinv;
    const float R00 = 1.f - 2.f * (qy * qy + qz * qz), R01 = 2.f * (qx * qy - qw * qz), R02 = 2.f * (qx * qz + qw * qy);
    const float R10 = 2.f * (qx * qy + qw * qz), R11 = 1.f - 2.f * (qx * qx + qz * qz), R12 = 2.f * (qy * qz - qw * qx);
    const float R20 = 2.f * (qx * qz - qw * qy), R21 = 2.f * (qy * qz + qw * qx), R22 = 1.f - 2.f * (qx * qx + qy * qy);
    float s0, s1, s2;
    if (p < 7) {
      s0 = FIXS[p][0]; s1 = FIXS[p][1]; s2 = FIXS[p][2];
    } else {
      const int b = (p - 7) * 3;
      s0 = s_learn[b]; s1 = s_learn[b + 1]; s2 = s_learn[b + 2];
    }
    const float vx = s0 * an[3], vy = s1 * an[4], vz = s2 * an[5];
    const float kx = R00 * vx + R10 * vy + R20 * vz + an[0];
    const float ky = R01 * vx + R11 * vy + R21 * vz + an[1];
    const float kz = R02 * vx + R12 * vy + R22 * vz + an[2];
    const float* P = proj + c * 16;
    const float h0 = P[0] * kx + P[1] * ky + P[2] * kz + P[3];
    const float h1 = P[4] * kx + P[5] * ky + P[6] * kz + P[7];
    const float h2 = P[8] * kx + P[9] * ky + P[10] * kz + P[11];
    const float zz = fmaxf(h2, 1e-5f);
    float px = h0 / zz / wh[c * 2 + 0];
    float py = h1 / zz / wh[c * 2 + 1];
    px = fminf(fmaxf(px, 0.f), 0.9999f);
    py = fminf(fmaxf(py, 0.f), 0.9999f);
    s_p2d[tid][0] = px;
    s_p2d[tid][1] = py;
  }
  __syncthreads();

  // phase 4: per-task corner BYTE offsets (fp8 layout) + bilinear weights;
  // tasks 312..319 get zero weights (loop tail padding)
  {
    constexpr int LBB[4] = {FT_L0, FT_L1, FT_L2, FT_L3};                 // bytes
    constexpr int CSB[4] = {2883584, 720896, 180224, 45056};             // H*W*256
    for (int t = tid; t < 320; t += 256) {
      const int pc = t >> 2, l = t & 3;
      if (pc >= 78) {
        s_off[t] = make_int4(0, 0, 0, 0);
        s_wt[t] = make_float4(0.f, 0.f, 0.f, 0.f);
        continue;
      }
      const int c = pc % 6;
      const int H = 64 >> l, W = 176 >> l;
      const float fx = s_p2d[pc][0] * (float)W - 0.5f;
      const float fy = s_p2d[pc][1] * (float)H - 0.5f;
      const float x0f = floorf(fx), y0f = floorf(fy);
      const float wx = fx - x0f, wy = fy - y0f;
      const int x0 = (int)x0f, y0 = (int)y0f;
      const float mx0 = (x0 >= 0) ? 1.f : 0.f;
      const float mx1 = (x0 + 1 < W) ? 1.f : 0.f;
      const float my0 = (y0 >= 0) ? 1.f : 0.f;
      const float my1 = (y0 + 1 < H) ? 1.f : 0.f;
      const int cx0 = max(x0, 0), cx1 = min(x0 + 1, W - 1);
      const int cy0 = max(y0, 0), cy1 = min(y0 + 1, H - 1);
      const int base = LBB[l] + c * CSB[l];
      int4 o;
      o.x = base + (cy0 * W + cx0) * 256;
      o.y = base + (cy0 * W + cx1) * 256;
      o.z = base + (cy1 * W + cx0) * 256;
      o.w = base + (cy1 * W + cx1) * 256;
      s_off[t] = o;
      float4 w4;
      w4.x = (1.f - wx) * (1.f - wy) * mx0 * my0;
      w4.y = wx * (1.f - wy) * mx1 * my0;
      w4.z = (1.f - wx) * wy * mx0 * my1;
      w4.w = wx * wy * mx1 * my1;
      s_wt[t] = w4;
    }
  }
  __syncthreads();

  // phase 5: fp8 gather. half-wave = one pc; 8 channels per lane.
  const int half = lane >> 5;
  const int sl = lane & 31;
  const int chb = sl * 8;       // byte offset of this lane's 8 fp8 channels
  const int g = sl >> 2;        // group of these channels
  v2f a0 = {0.f, 0.f}, a1 = {0.f, 0.f}, a2 = {0.f, 0.f}, a3 = {0.f, 0.f};
  const unsigned char* fb = featF;
  const unsigned short* wrow = &s_w[g * 328];
  const int pcb = wave * 2 + half;
#pragma unroll 2
  for (int it = 0; it < 10; ++it) {
    const int pc = pcb + it * 8;   // < 80 (tasks >= 312 are zero-weighted)
    const int t0 = pc * 4;
    const uint2 wq = *(const uint2*)&wrow[t0];  // 4 bf16 level-weights
    float wgl[4];
    wgl[0] = __uint_as_float(wq.x << 16);
    wgl[1] = __uint_as_float(wq.x & 0xffff0000u);
    wgl[2] = __uint_as_float(wq.y << 16);
    wgl[3] = __uint_as_float(wq.y & 0xffff0000u);
#pragma unroll
    for (int l4 = 0; l4 < 4; ++l4) {
      const int t = t0 + l4;
      const int4 o = s_off[t];
      const float4 bw = s_wt[t];
      const float wg = wgl[l4];
      const uint2 u0 = *(const uint2*)(fb + (o.x + chb));
      const uint2 u1 = *(const uint2*)(fb + (o.y + chb));
      const uint2 u2 = *(const uint2*)(fb + (o.z + chb));
      const uint2 u3 = *(const uint2*)(fb + (o.w + chb));
      const v2f w0 = {bw.x * wg, bw.x * wg};
      const v2f w1 = {bw.y * wg, bw.y * wg};
      const v2f w2 = {bw.z * wg, bw.z * wg};
      const v2f w3 = {bw.w * wg, bw.w * wg};
      a0 += __builtin_amdgcn_cvt_pk_f32_fp8((int)u0.x, false) * w0;
      a1 += __builtin_amdgcn_cvt_pk_f32_fp8((int)u0.x, true)  * w0;
      a2 += __builtin_amdgcn_cvt_pk_f32_fp8((int)u0.y, false) * w0;
      a3 += __builtin_amdgcn_cvt_pk_f32_fp8((int)u0.y, true)  * w0;
      a0 += __builtin_amdgcn_cvt_pk_f32_fp8((int)u1.x, false) * w1;
      a1 += __builtin_amdgcn_cvt_pk_f32_fp8((int)u1.x, true)  * w1;
      a2 += __builtin_amdgcn_cvt_pk_f32_fp8((int)u1.y, false) * w1;
      a3 += __builtin_amdgcn_cvt_pk_f32_fp8((int)u1.y, true)  * w1;
      a0 += __builtin_amdgcn_cvt_pk_f32_fp8((int)u2.x, false) * w2;
      a1 += __builtin_amdgcn_cvt_pk_f32_fp8((int)u2.x, true)  * w2;
      a2 += __builtin_amdgcn_cvt_pk_f32_fp8((int)u2.y, false) * w2;
      a3 += __builtin_amdgcn_cvt_pk_f32_fp8((int)u2.y, true)  * w2;
      a0 += __builtin_amdgcn_cvt_pk_f32_fp8((int)u3.x, false) * w3;
      a1 += __builtin_amdgcn_cvt_pk_f32_fp8((int)u3.x, true)  * w3;
      a2 += __builtin_amdgcn_cvt_pk_f32_fp8((int)u3.y, false) * w3;
      a3 += __builtin_amdgcn_cvt_pk_f32_fp8((int)u3.y, true)  * w3;
    }
  }
  const int wr = wave * 2 + half;  // 0..7
  {
    float4 r0; r0.x = a0.x; r0.y = a0.y; r0.z = a1.x; r0.w = a1.y;
    float4 r1; r1.x = a2.x; r1.y = a2.y; r1.z = a3.x; r1.w = a3.y;
    *(float4*)&s_red[wr][chb] = r0;
    *(float4*)&s_red[wr][chb + 4] = r1;
  }
  __syncthreads();
  // final: thread tid sums channel tid over 8 partials
  {
    float sum = 0.f;
#pragma unroll
    for (int r = 0; r < 8; ++r) sum += s_red[r][tid];
    featsB[n * 256 + tid] = (unsigned short)f2bf(sum);
  }
}

// MFMA GEMM: out = featsB(4096x256) @ Wob^T + b_out + resid. grid (4,64)
__global__ __launch_bounds__(256) void k_out_mfma(
    const unsigned short* __restrict__ Ab, const unsigned short* __restrict__ Bb,
    const float* __restrict__ bias, const float* __restrict__ resid,
    float* __restrict__ out) {
  const int tid = threadIdx.x;
  const int w = tid >> 6, lane = tid & 63;
  const int ml = lane & 15, q = lane >> 4;
  const int n0 = blockIdx.x * 64;
  const int m0 = blockIdx.y * 64;
  f32x4 acc[4] = {{0.f, 0.f, 0.f, 0.f}, {0.f, 0.f, 0.f, 0.f},
                  {0.f, 0.f, 0.f, 0.f}, {0.f, 0.f, 0.f, 0.f}};
  const unsigned short* Ap = Ab + (m0 + w * 16 + ml) * 256 + q * 8;
  const unsigned short* Bp = Bb + (n0 + ml) * 256 + q * 8;
#pragma unroll
  for (int kk = 0; kk < 8; ++kk) {
    const bf16x8 a = *(const bf16x8*)(Ap + kk * 32);
#pragma unroll
    for (int nt = 0; nt < 4; ++nt) {
      const bf16x8 b = *(const bf16x8*)(Bp + nt * 16 * 256 + kk * 32);
      acc[nt] = __builtin_amdgcn_mfma_f32_16x16x32_bf16(a, b, acc[nt], 0, 0, 0);
    }
  }
  const int rowb = m0 + w * 16 + q * 4;
#pragma unroll
  for (int nt = 0; nt < 4; ++nt) {
    const int col = n0 + nt * 16 + ml;
    const float b = bias[col];
#pragma unroll
    for (int r = 0; r < 4; ++r) {
      const int row = rowb + r;
      out[row * 256 + col] = acc[nt][r] + b + resid[row * 256 + col];
    }
  }
}

extern "C" void kernel_launch(void* const* d_in, const int* in_sizes, int n_in,
                              void* d_out, int out_size, void* d_ws, size_t ws_size,
                              hipStream_t stream) {
  (void)in_sizes; (void)n_in; (void)out_size; (void)ws_size;
  const float* iw      = (const float*)d_in[1];
  const float* anchor  = (const float*)d_in[2];
  const float* f0      = (const float*)d_in[3];
  const float* f1      = (const float*)d_in[4];
  const float* f2      = (const float*)d_in[5];
  const float* f3      = (const float*)d_in[6];
  const float* proj    = (const float*)d_in[7];
  const float* wh      = (const float*)d_in[8];
  const float* W_learn = (const float*)d_in[9];
  const float* b_learn = (const float*)d_in[10];
  const float* W_wts   = (const float*)d_in[11];
  const float* b_wts   = (const float*)d_in[12];
  const float* W_out   = (const float*)d_in[13];
  const float* b_out   = (const float*)d_in[14];
  float* out = (float*)d_out;
  float* ws = (float*)d_ws;
  unsigned char*  featF   = (unsigned char*)ws;
  unsigned short* logitsB = (unsigned short*)(ws + WS_LOGB);
  unsigned short* featsB  = (unsigned short*)(ws + WS_FEATB);
  float*          learn   = ws + WS_LEARN;
  unsigned short* Ab      = (unsigned short*)(ws + WS_AB);
  unsigned short* Bb      = (unsigned short*)(ws + WS_BB);
  unsigned short* Wob     = (unsigned short*)(ws + WS_WOB);

  k_transpose_all<<<dim3(12, 64, 48), 256, 0, stream>>>(f0, f1, f2, f3, featF);
  k_prep_pack<<<1728, 256, 0, stream>>>(iw, W_wts, W_learn, W_out, Ab, Bb, Wob);
  k_wts_mfma<<<dim3(40, 64), 256, 0, stream>>>(Ab, Bb, b_wts, b_learn, logitsB, learn);
  k_sample<<<4096, 256, 0, stream>>>(anchor, logitsB, learn, featF, proj, wh, featsB);
  k_out_mfma<<<dim3(4, 64), 256, 0, stream>>>(featsB, Wob, b_out, iw, out);
}

// Round 9
// 303.851 us; speedup vs baseline: 1.5826x; 1.0728x over previous
//
#include <hip/hip_runtime.h>
#include <math.h>

// ---------------------------------------------------------------------------
// DeformableFeatureAggregation — MI355X
// Pipeline (5 launches):
//   k_transpose_all : feat L0..L3 (6,256,H,W) fp32 -> featF (6,H,W,256) fp8 e4m3
//   k_prep_pack     : iw->Ab bf16 ; [W_wts|W_learn]->Bb bf16 N-major ; W_out->Wob
//   k_wts_mfma      : MFMA -> logitsB bf16 (4096x2496) + learn fp32 (4096x18)
//   k_sample        : FUSED per-anchor block: task-ordered softmax (LDS),
//                     projection, task tables (LDS, padded to 320 tasks),
//                     fp8 gather: QUARTER-wave = one pc (16 lanes x 16B uint4),
//                     shfl_xor reduction
//   k_out_mfma      : MFMA out = featsB @ W_out^T + b_out + iw (fp32)
// Workspace (float offsets):
//   featF  : bytes 0..22978560                (f 0..5744640)
//   logitsB: f 5744640   (4096x2496 ush)  -> 10856448
//   featsB : f 10856448  (4096x256 ush)   -> 11380736
//   learn  : f 11380736  (4096x18 f)      -> 11454464
//   Ab     : f 11454464  (4096x256 ush)   -> 11978752
//   Bb     : f 11978752  (2560x256 ush)   -> 12306432
//   Wob    : f 12306432  (256x256 ush)    -> 12339200   (~49 MB)
// ---------------------------------------------------------------------------

#define FT_L0 0
#define FT_L1 17301504
#define FT_L2 21626880
#define FT_L3 22708224
#define WS_LOGB 5744640
#define WS_FEATB 10856448
#define WS_LEARN 11380736
#define WS_AB 11454464
#define WS_BB 11978752
#define WS_WOB 12306432

typedef float v2f __attribute__((ext_vector_type(2)));
typedef __attribute__((ext_vector_type(8))) short bf16x8;
typedef __attribute__((ext_vector_type(4))) float f32x4;

__device__ const float FIXS[7][3] = {
    {0.f, 0.f, 0.f},  {0.45f, 0.f, 0.f}, {-0.45f, 0.f, 0.f}, {0.f, 0.45f, 0.f},
    {0.f, -0.45f, 0.f}, {0.f, 0.f, 0.45f}, {0.f, 0.f, -0.45f}};

__device__ __forceinline__ unsigned int f2bf(float f) {
  unsigned int u = __float_as_uint(f);
  u += 0x7fffu + ((u >> 16) & 1u);  // RTNE
  return u >> 16;
}
__device__ __forceinline__ float bf2f(unsigned short u) {
  return __uint_as_float(((unsigned int)u) << 16);
}

// All 4 levels: (6,256,H,W) fp32 -> (6,H,W,256) fp8 e4m3. grid (12, 64, 48)
__global__ __launch_bounds__(256) void k_transpose_all(
    const float* __restrict__ f0, const float* __restrict__ f1,
    const float* __restrict__ f2, const float* __restrict__ f3,
    unsigned char* __restrict__ featF) {
  const int bx = blockIdx.x;
  const float* src;
  unsigned char* dst;
  int H, W, xt;
  if (bx < 6)       { src = f0; dst = featF + FT_L0; H = 64; W = 176; xt = bx * 32; }
  else if (bx < 9)  { src = f1; dst = featF + FT_L1; H = 32; W = 88;  xt = (bx - 6) * 32; }
  else if (bx < 11) { src = f2; dst = featF + FT_L2; H = 16; W = 44;  xt = (bx - 9) * 32; }
  else              { src = f3; dst = featF + FT_L3; H = 8;  W = 22;  xt = 0; }
  const int y = blockIdx.y;
  if (y >= H) return;
  __shared__ float tile[32][33];
  const int tid = threadIdx.x;
  const int i = tid & 31;
  const int j = tid >> 5;
  const int c = blockIdx.z >> 3;
  const int cht = (blockIdx.z & 7) * 32;
#pragma unroll
  for (int jj = j; jj < 32; jj += 8) {
    int x = xt + i;
    float v = 0.f;
    if (x < W) v = src[((c * 256 + cht + jj) * H + y) * W + x];
    tile[jj][i] = v;
  }
  __syncthreads();
  // write: thread -> (x = xt + tid>>3, channel quad q = tid&7); 4 fp8 per u32
  const int q = tid & 7;
  const int xw = tid >> 3;
  const int x = xt + xw;
  if (x < W) {
    const float v0 = tile[q * 4 + 0][xw];
    const float v1 = tile[q * 4 + 1][xw];
    const float v2 = tile[q * 4 + 2][xw];
    const float v3 = tile[q * 4 + 3][xw];
    int pk = __builtin_amdgcn_cvt_pk_fp8_f32(v0, v1, 0, false);
    pk = __builtin_amdgcn_cvt_pk_fp8_f32(v2, v3, pk, true);
    *(unsigned int*)(dst + (((c * H + y) * W + x) * 256) + cht + q * 4) =
        (unsigned int)pk;
  }
}

// Fused packing: bx<1024 -> Ab ; <1664 -> Bb tile ; else Wob tile. grid 1728.
__global__ __launch_bounds__(256) void k_prep_pack(
    const float* __restrict__ iw, const float* __restrict__ Ww,
    const float* __restrict__ Wl, const float* __restrict__ Wo,
    unsigned short* __restrict__ Ab, unsigned short* __restrict__ Bb,
    unsigned short* __restrict__ Wob) {
  __shared__ unsigned short tile[32][33];
  const int tid = threadIdx.x;
  const int bx = blockIdx.x;
  if (bx < 1024) {
    const int i = bx * 256 + tid;
    const float4 v = ((const float4*)iw)[i];
    uint2 o;
    o.x = f2bf(v.x) | (f2bf(v.y) << 16);
    o.y = f2bf(v.z) | (f2bf(v.w) << 16);
    ((uint2*)Ab)[i] = o;
    return;
  }
  const int i = tid & 31;
  const int r = tid >> 5;
  if (bx < 1664) {
    const int idx = bx - 1024;
    const int j0 = (idx % 80) * 32;
    const int k0 = (idx / 80) * 32;
#pragma unroll
    for (int rr = r; rr < 32; rr += 8) {
      const int k = k0 + rr, j = j0 + i;
      float v = 0.f;
      if (j < 2496) v = Ww[k * 2496 + j];
      else if (j < 2514) v = Wl[k * 18 + (j - 2496)];
      tile[rr][i] = (unsigned short)f2bf(v);
    }
    __syncthreads();
#pragma unroll
    for (int rr = r; rr < 32; rr += 8)
      Bb[(j0 + rr) * 256 + k0 + i] = tile[i][rr];
  } else {
    const int idx = bx - 1664;
    const int j0 = (idx & 7) * 32;
    const int k0 = (idx >> 3) * 32;
#pragma unroll
    for (int rr = r; rr < 32; rr += 8)
      tile[rr][i] = (unsigned short)f2bf(Wo[(k0 + rr) * 256 + j0 + i]);
    __syncthreads();
#pragma unroll
    for (int rr = r; rr < 32; rr += 8)
      Wob[(j0 + rr) * 256 + k0 + i] = tile[i][rr];
  }
}

// MFMA GEMM: [logits | learn] = Ab(4096x256) @ Bb^T + bias. grid (40,64)
__global__ __launch_bounds__(256) void k_wts_mfma(
    const unsigned short* __restrict__ Ab, const unsigned short* __restrict__ Bb,
    const float* __restrict__ b_wts, const float* __restrict__ b_learn,
    unsigned short* __restrict__ logitsB, float* __restrict__ learn) {
  const int tid = threadIdx.x;
  const int w = tid >> 6, lane = tid & 63;
  const int ml = lane & 15, q = lane >> 4;
  const int n0 = blockIdx.x * 64;
  const int m0 = blockIdx.y * 64;
  f32x4 acc[4] = {{0.f, 0.f, 0.f, 0.f}, {0.f, 0.f, 0.f, 0.f},
                  {0.f, 0.f, 0.f, 0.f}, {0.f, 0.f, 0.f, 0.f}};
  const unsigned short* Ap = Ab + (m0 + w * 16 + ml) * 256 + q * 8;
  const unsigned short* Bp = Bb + (n0 + ml) * 256 + q * 8;
#pragma unroll
  for (int kk = 0; kk < 8; ++kk) {
    const bf16x8 a = *(const bf16x8*)(Ap + kk * 32);
#pragma unroll
    for (int nt = 0; nt < 4; ++nt) {
      const bf16x8 b = *(const bf16x8*)(Bp + nt * 16 * 256 + kk * 32);
      acc[nt] = __builtin_amdgcn_mfma_f32_16x16x32_bf16(a, b, acc[nt], 0, 0, 0);
    }
  }
  const int rowb = m0 + w * 16 + q * 4;
#pragma unroll
  for (int nt = 0; nt < 4; ++nt) {
    const int col = n0 + nt * 16 + ml;
    if (col < 2496) {
      const float b = b_wts[col];
#pragma unroll
      for (int r = 0; r < 4; ++r)
        logitsB[(rowb + r) * 2496 + col] = (unsigned short)f2bf(acc[nt][r] + b);
    } else if (col < 2514) {
      const float b = b_learn[col - 2496];
#pragma unroll
      for (int r = 0; r < 4; ++r) {
        float v = fminf(fmaxf(acc[nt][r] + b, -9.21f), 9.21f);
        learn[(rowb + r) * 18 + (col - 2496)] = 1.f / (1.f + expf(-v)) - 0.5f;
      }
    }
  }
}

// Fused per-anchor sampler. grid 4096 x 256.
// phase 5: quarter-wave = one pc (16 lanes x 16 fp8 channels via uint4).
__global__ __launch_bounds__(256, 6) void k_sample(
    const float* __restrict__ anchor, const unsigned short* __restrict__ logitsB,
    const float* __restrict__ learn_g, const unsigned char* __restrict__ featF,
    const float* __restrict__ proj, const float* __restrict__ wh,
    unsigned short* __restrict__ featsB) {
  const int n = blockIdx.x;
  const int tid = threadIdx.x;
  const int lane = tid & 63;
  const int wave = tid >> 6;
  __shared__ unsigned short s_w[8 * 328];  // bf16 softmax weights [g][t], pad 328
  __shared__ float s_p2d[78][2];
  __shared__ float s_learn[18];
  __shared__ int4 s_off[320];    // corner BYTE offsets per task t (pad to 320)
  __shared__ float4 s_wt[320];   // bilinear corner weights per task t
  __shared__ float s_red[4][256];

  // phase 1: logits -> LDS, permuted to task order t=(p*6+c)*4+l from
  // s = c*52 + l*13 + p (softmax is order-invariant over the 312 axis)
  for (int i = tid; i < 2496; i += 256) {
    const int s = i >> 3, g = i & 7;
    const int c = s / 52;
    const int r = s - c * 52;
    const int l = r / 13;
    const int p = r - l * 13;
    s_w[g * 328 + (p * 6 + c) * 4 + l] = logitsB[n * 2496 + i];
  }
  if (tid < 64) s_w[(tid >> 3) * 328 + 312 + (tid & 7)] = 0;  // zero pad tasks
  if (tid < 18) s_learn[tid] = learn_g[n * 18 + tid];
  __syncthreads();

  // phase 2: softmax over the 312 tasks per group; wave w -> groups 2w, 2w+1
#pragma unroll
  for (int gg = 0; gg < 2; ++gg) {
    unsigned short* row = &s_w[(wave * 2 + gg) * 328];
    float l[5];
    float mx = -1e30f;
#pragma unroll
    for (int i = 0; i < 5; ++i) {
      const int s = lane + i * 64;
      l[i] = (s < 312) ? bf2f(row[s]) : -1e30f;
      mx = fmaxf(mx, l[i]);
    }
    for (int off = 32; off; off >>= 1) mx = fmaxf(mx, __shfl_xor(mx, off));
    float sum = 0.f;
#pragma unroll
    for (int i = 0; i < 5; ++i) {
      l[i] = __expf(l[i] - mx);
      sum += l[i];
    }
    for (int off = 32; off; off >>= 1) sum += __shfl_xor(sum, off);
    const float inv = 1.f / sum;
#pragma unroll
    for (int i = 0; i < 5; ++i) {
      const int s = lane + i * 64;
      if (s < 312) row[s] = (unsigned short)f2bf(l[i] * inv);
    }
  }

  // phase 3: projection of 78 (pt,cam) pairs
  if (tid < 78) {
    const int p = tid / 6, c = tid % 6;
    const float* an = anchor + n * 11;
    float qw = an[6], qx = an[7], qy = an[8], qz = an[9];
    const float qinv = 1.f / sqrtf(qw * qw + qx * qx + qy * qy + qz * qz);
    qw *= qinv; qx *= qinv; qy *= qinv; qz *= qinv;
    const float R00 = 1.f - 2.f * (qy * qy + qz * qz), R01 = 2.f * (qx * qy - qw * qz), R02 = 2.f * (qx * qz + qw * qy);
    const float R10 = 2.f * (qx * qy + qw * qz), R11 = 1.f - 2.f * (qx * qx + qz * qz), R12 = 2.f * (qy * qz - qw * qx);
    const float R20 = 2.f * (qx * qz - qw * qy), R21 = 2.f * (qy * qz + qw * qx), R22 = 1.f - 2.f * (qx * qx + qy * qy);
    float s0, s1, s2;
    if (p < 7) {
      s0 = FIXS[p][0]; s1 = FIXS[p][1]; s2 = FIXS[p][2];
    } else {
      const int b = (p - 7) * 3;
      s0 = s_learn[b]; s1 = s_learn[b + 1]; s2 = s_learn[b + 2];
    }
    const float vx = s0 * an[3], vy = s1 * an[4], vz = s2 * an[5];
    const float kx = R00 * vx + R10 * vy + R20 * vz + an[0];
    const float ky = R01 * vx + R11 * vy + R21 * vz + an[1];
    const float kz = R02 * vx + R12 * vy + R22 * vz + an[2];
    const float* P = proj + c * 16;
    const float h0 = P[0] * kx + P[1] * ky + P[2] * kz + P[3];
    const float h1 = P[4] * kx + P[5] * ky + P[6] * kz + P[7];
    const float h2 = P[8] * kx + P[9] * ky + P[10] * kz + P[11];
    const float zz = fmaxf(h2, 1e-5f);
    float px = h0 / zz / wh[c * 2 + 0];
    float py = h1 / zz / wh[c * 2 + 1];
    px = fminf(fmaxf(px, 0.f), 0.9999f);
    py = fminf(fmaxf(py, 0.f), 0.9999f);
    s_p2d[tid][0] = px;
    s_p2d[tid][1] = py;
  }
  __syncthreads();

  // phase 4: per-task corner BYTE offsets (fp8 layout) + bilinear weights;
  // tasks 312..319 get zero weights (loop tail padding)
  {
    constexpr int LBB[4] = {FT_L0, FT_L1, FT_L2, FT_L3};                 // bytes
    constexpr int CSB[4] = {2883584, 720896, 180224, 45056};             // H*W*256
    for (int t = tid; t < 320; t += 256) {
      const int pc = t >> 2, l = t & 3;
      if (pc >= 78) {
        s_off[t] = make_int4(0, 0, 0, 0);
        s_wt[t] = make_float4(0.f, 0.f, 0.f, 0.f);
        continue;
      }
      const int c = pc % 6;
      const int H = 64 >> l, W = 176 >> l;
      const float fx = s_p2d[pc][0] * (float)W - 0.5f;
      const float fy = s_p2d[pc][1] * (float)H - 0.5f;
      const float x0f = floorf(fx), y0f = floorf(fy);
      const float wx = fx - x0f, wy = fy - y0f;
      const int x0 = (int)x0f, y0 = (int)y0f;
      const float mx0 = (x0 >= 0) ? 1.f : 0.f;
      const float mx1 = (x0 + 1 < W) ? 1.f : 0.f;
      const float my0 = (y0 >= 0) ? 1.f : 0.f;
      const float my1 = (y0 + 1 < H) ? 1.f : 0.f;
      const int cx0 = max(x0, 0), cx1 = min(x0 + 1, W - 1);
      const int cy0 = max(y0, 0), cy1 = min(y0 + 1, H - 1);
      const int base = LBB[l] + c * CSB[l];
      int4 o;
      o.x = base + (cy0 * W + cx0) * 256;
      o.y = base + (cy0 * W + cx1) * 256;
      o.z = base + (cy1 * W + cx0) * 256;
      o.w = base + (cy1 * W + cx1) * 256;
      s_off[t] = o;
      float4 w4;
      w4.x = (1.f - wx) * (1.f - wy) * mx0 * my0;
      w4.y = wx * (1.f - wy) * mx1 * my0;
      w4.z = (1.f - wx) * wy * mx0 * my1;
      w4.w = wx * wy * mx1 * my1;
      s_wt[t] = w4;
    }
  }
  __syncthreads();

  // phase 5: fp8 gather. quarter-wave = one pc; 16 fp8 channels per lane.
  const int q = lane >> 4;      // quarter 0..3
  const int ql = lane & 15;     // lane in quarter
  const int chb = ql * 16;      // byte offset of this lane's 16 fp8 channels
  const int g = ql >> 1;        // group (32 channels each)
  v2f acc[8];
#pragma unroll
  for (int k = 0; k < 8; ++k) acc[k] = (v2f){0.f, 0.f};
  const unsigned char* fb = featF;
  const unsigned short* wrow = &s_w[g * 328];
  const int pcb = wave * 4 + q;
#pragma unroll
  for (int it = 0; it < 5; ++it) {
    const int pc = pcb + it * 16;   // < 80 (tasks >= 312 are zero-weighted)
    const int t0 = pc * 4;
    const uint2 wq = *(const uint2*)&wrow[t0];  // 4 bf16 level-weights
    float wgl[4];
    wgl[0] = __uint_as_float(wq.x << 16);
    wgl[1] = __uint_as_float(wq.x & 0xffff0000u);
    wgl[2] = __uint_as_float(wq.y << 16);
    wgl[3] = __uint_as_float(wq.y & 0xffff0000u);
#pragma unroll
    for (int l4 = 0; l4 < 4; ++l4) {
      const int t = t0 + l4;
      const int4 o = s_off[t];
      const float4 bw = s_wt[t];
      const float wg = wgl[l4];
      const uint4 u0 = *(const uint4*)(fb + (o.x + chb));
      const uint4 u1 = *(const uint4*)(fb + (o.y + chb));
      const uint4 u2 = *(const uint4*)(fb + (o.z + chb));
      const uint4 u3 = *(const uint4*)(fb + (o.w + chb));
      const float s0 = bw.x * wg, s1 = bw.y * wg, s2 = bw.z * wg, s3 = bw.w * wg;
      const v2f w0 = {s0, s0}, w1 = {s1, s1}, w2 = {s2, s2}, w3 = {s3, s3};
      acc[0] += __builtin_amdgcn_cvt_pk_f32_fp8((int)u0.x, false) * w0;
      acc[1] += __builtin_amdgcn_cvt_pk_f32_fp8((int)u0.x, true)  * w0;
      acc[2] += __builtin_amdgcn_cvt_pk_f32_fp8((int)u0.y, false) * w0;
      acc[3] += __builtin_amdgcn_cvt_pk_f32_fp8((int)u0.y, true)  * w0;
      acc[4] += __builtin_amdgcn_cvt_pk_f32_fp8((int)u0.z, false) * w0;
      acc[5] += __builtin_amdgcn_cvt_pk_f32_fp8((int)u0.z, true)  * w0;
      acc[6] += __builtin_amdgcn_cvt_pk_f32_fp8((int)u0.w, false) * w0;
      acc[7] += __builtin_amdgcn_cvt_pk_f32_fp8((int)u0.w, true)  * w0;
      acc[0] += __builtin_amdgcn_cvt_pk_f32_fp8((int)u1.x, false) * w1;
      acc[1] += __builtin_amdgcn_cvt_pk_f32_fp8((int)u1.x, true)  * w1;
      acc[2] += __builtin_amdgcn_cvt_pk_f32_fp8((int)u1.y, false) * w1;
      acc[3] += __builtin_amdgcn_cvt_pk_f32_fp8((int)u1.y, true)  * w1;
      acc[4] += __builtin_amdgcn_cvt_pk_f32_fp8((int)u1.z, false) * w1;
      acc[5] += __builtin_amdgcn_cvt_pk_f32_fp8((int)u1.z, true)  * w1;
      acc[6] += __builtin_amdgcn_cvt_pk_f32_fp8((int)u1.w, false) * w1;
      acc[7] += __builtin_amdgcn_cvt_pk_f32_fp8((int)u1.w, true)  * w1;
      acc[0] += __builtin_amdgcn_cvt_pk_f32_fp8((int)u2.x, false) * w2;
      acc[1] += __builtin_amdgcn_cvt_pk_f32_fp8((int)u2.x, true)  * w2;
      acc[2] += __builtin_amdgcn_cvt_pk_f32_fp8((int)u2.y, false) * w2;
      acc[3] += __builtin_amdgcn_cvt_pk_f32_fp8((int)u2.y, true)  * w2;
      acc[4] += __builtin_amdgcn_cvt_pk_f32_fp8((int)u2.z, false) * w2;
      acc[5] += __builtin_amdgcn_cvt_pk_f32_fp8((int)u2.z, true)  * w2;
      acc[6] += __builtin_amdgcn_cvt_pk_f32_fp8((int)u2.w, false) * w2;
      acc[7] += __builtin_amdgcn_cvt_pk_f32_fp8((int)u2.w, true)  * w2;
      acc[0] += __builtin_amdgcn_cvt_pk_f32_fp8((int)u3.x, false) * w3;
      acc[1] += __builtin_amdgcn_cvt_pk_f32_fp8((int)u3.x, true)  * w3;
      acc[2] += __builtin_amdgcn_cvt_pk_f32_fp8((int)u3.y, false) * w3;
      acc[3] += __builtin_amdgcn_cvt_pk_f32_fp8((int)u3.y, true)  * w3;
      acc[4] += __builtin_amdgcn_cvt_pk_f32_fp8((int)u3.z, false) * w3;
      acc[5] += __builtin_amdgcn_cvt_pk_f32_fp8((int)u3.z, true)  * w3;
      acc[6] += __builtin_amdgcn_cvt_pk_f32_fp8((int)u3.w, false) * w3;
      acc[7] += __builtin_amdgcn_cvt_pk_f32_fp8((int)u3.w, true)  * w3;
    }
  }
  // cross-quarter reduction: quarters hold same channels (ql) for different pcs
#pragma unroll
  for (int k = 0; k < 8; ++k) {
    v2f b;
    b.x = __shfl_xor(acc[k].x, 16);
    b.y = __shfl_xor(acc[k].y, 16);
    acc[k] += b;
    b.x = __shfl_xor(acc[k].x, 32);
    b.y = __shfl_xor(acc[k].y, 32);
    acc[k] += b;
  }
  if (lane < 16) {
    float* dst = &s_red[wave][ql * 16];
    *(float4*)(dst + 0)  = make_float4(acc[0].x, acc[0].y, acc[1].x, acc[1].y);
    *(float4*)(dst + 4)  = make_float4(acc[2].x, acc[2].y, acc[3].x, acc[3].y);
    *(float4*)(dst + 8)  = make_float4(acc[4].x, acc[4].y, acc[5].x, acc[5].y);
    *(float4*)(dst + 12) = make_float4(acc[6].x, acc[6].y, acc[7].x, acc[7].y);
  }
  __syncthreads();
  // final: thread tid sums channel tid over 4 wave partials
  {
    const float sum = s_red[0][tid] + s_red[1][tid] + s_red[2][tid] + s_red[3][tid];
    featsB[n * 256 + tid] = (unsigned short)f2bf(sum);
  }
}

// MFMA GEMM: out = featsB(4096x256) @ Wob^T + b_out + resid. grid (4,64)
__global__ __launch_bounds__(256) void k_out_mfma(
    const unsigned short* __restrict__ Ab, const unsigned short* __restrict__ Bb,
    const float* __restrict__ bias, const float* __restrict__ resid,
    float* __restrict__ out) {
  const int tid = threadIdx.x;
  const int w = tid >> 6, lane = tid & 63;
  const int ml = lane & 15, q = lane >> 4;
  const int n0 = blockIdx.x * 64;
  const int m0 = blockIdx.y * 64;
  f32x4 acc[4] = {{0.f, 0.f, 0.f, 0.f}, {0.f, 0.f, 0.f, 0.f},
                  {0.f, 0.f, 0.f, 0.f}, {0.f, 0.f, 0.f, 0.f}};
  const unsigned short* Ap = Ab + (m0 + w * 16 + ml) * 256 + q * 8;
  const unsigned short* Bp = Bb + (n0 + ml) * 256 + q * 8;
#pragma unroll
  for (int kk = 0; kk < 8; ++kk) {
    const bf16x8 a = *(const bf16x8*)(Ap + kk * 32);
#pragma unroll
    for (int nt = 0; nt < 4; ++nt) {
      const bf16x8 b = *(const bf16x8*)(Bp + nt * 16 * 256 + kk * 32);
      acc[nt] = __builtin_amdgcn_mfma_f32_16x16x32_bf16(a, b, acc[nt], 0, 0, 0);
    }
  }
  const int rowb = m0 + w * 16 + q * 4;
#pragma unroll
  for (int nt = 0; nt < 4; ++nt) {
    const int col = n0 + nt * 16 + ml;
    const float b = bias[col];
#pragma unroll
    for (int r = 0; r < 4; ++r) {
      const int row = rowb + r;
      out[row * 256 + col] = acc[nt][r] + b + resid[row * 256 + col];
    }
  }
}

extern "C" void kernel_launch(void* const* d_in, const int* in_sizes, int n_in,
                              void* d_out, int out_size, void* d_ws, size_t ws_size,
                              hipStream_t stream) {
  (void)in_sizes; (void)n_in; (void)out_size; (void)ws_size;
  const float* iw      = (const float*)d_in[1];
  const float* anchor  = (const float*)d_in[2];
  const float* f0      = (const float*)d_in[3];
  const float* f1      = (const float*)d_in[4];
  const float* f2      = (const float*)d_in[5];
  const float* f3      = (const float*)d_in[6];
  const float* proj    = (const float*)d_in[7];
  const float* wh      = (const float*)d_in[8];
  const float* W_learn = (const float*)d_in[9];
  const float* b_learn = (const float*)d_in[10];
  const float* W_wts   = (const float*)d_in[11];
  const float* b_wts   = (const float*)d_in[12];
  const float* W_out   = (const float*)d_in[13];
  const float* b_out   = (const float*)d_in[14];
  float* out = (float*)d_out;
  float* ws = (float*)d_ws;
  unsigned char*  featF   = (unsigned char*)ws;
  unsigned short* logitsB = (unsigned short*)(ws + WS_LOGB);
  unsigned short* featsB  = (unsigned short*)(ws + WS_FEATB);
  float*          learn   = ws + WS_LEARN;
  unsigned short* Ab      = (unsigned short*)(ws + WS_AB);
  unsigned short* Bb      = (unsigned short*)(ws + WS_BB);
  unsigned short* Wob     = (unsigned short*)(ws + WS_WOB);

  k_transpose_all<<<dim3(12, 64, 48), 256, 0, stream>>>(f0, f1, f2, f3, featF);
  k_prep_pack<<<1728, 256, 0, stream>>>(iw, W_wts, W_learn, W_out, Ab, Bb, Wob);
  k_wts_mfma<<<dim3(40, 64), 256, 0, stream>>>(Ab, Bb, b_wts, b_learn, logitsB, learn);
  k_sample<<<4096, 256, 0, stream>>>(anchor, logitsB, learn, featF, proj, wh, featsB);
  k_out_mfma<<<dim3(4, 64), 256, 0, stream>>>(featsB, Wob, b_out, iw, out);
}